// Round 6
// baseline (420.771 us; speedup 1.0000x reference)
//
#include <hip/hip_runtime.h>
#include <math.h>

#define DD 64   // feature dim

typedef _Float16 h2 __attribute__((ext_vector_type(2)));
typedef _Float16 h4 __attribute__((ext_vector_type(4)));
typedef _Float16 h8 __attribute__((ext_vector_type(8)));
typedef float f32x4 __attribute__((ext_vector_type(4)));

// ---- W -> MFMA A-fragment pre-shuffle (fp16), all layers at once ----
// wf layout: [layer][colTile c:16][kstep s:2][lane:64][j:8]
// element = W[k = s*32 + (lane>>4)*8 + j][feat = c*16 + (lane&15)]
// (same indexing serves as A-operand with row = lane&15 = feature)
__global__ __launch_bounds__(64) void k_wconv(
    const float* __restrict__ Wq, const float* __restrict__ Wk,
    const float* __restrict__ Wv, const float* __restrict__ Ws,
    _Float16* __restrict__ wf)
{
  int bid = blockIdx.x;          // layer*32 + c*2 + s
  int layer = bid >> 5;
  int c = (bid >> 1) & 15;
  int s = bid & 1;
  int lane = threadIdx.x;
  int col = c * 16 + (lane & 15);
  int mi = col >> 6;
  const float* W = (mi == 0 ? Wq : mi == 1 ? Wk : mi == 2 ? Wv : Ws)
                   + (size_t)layer * DD * DD;
  int colw = col & 63;
  _Float16* o = wf + ((((size_t)(layer * 16 + c)) * 2 + s) * 64 + lane) * 8;
  #pragma unroll
  for (int j = 0; j < 8; ++j) {
    int k = s * 32 + (lane >> 4) * 8 + j;
    o[j] = (_Float16)W[k * DD + colw];
  }
}

// fp32 -> fp16 convert (8 elems/thread)
__global__ __launch_bounds__(256) void k_xconv(
    const float* __restrict__ x, _Float16* __restrict__ xb, int total8)
{
  int i = blockIdx.x * 256 + threadIdx.x;
  if (i >= total8) return;
  float4 a = ((const float4*)x)[i * 2];
  float4 b = ((const float4*)x)[i * 2 + 1];
  h8 o;
  o[0] = (_Float16)a.x; o[1] = (_Float16)a.y; o[2] = (_Float16)a.z; o[3] = (_Float16)a.w;
  o[4] = (_Float16)b.x; o[5] = (_Float16)b.y; o[6] = (_Float16)b.z; o[7] = (_Float16)b.w;
  *(h8*)(xb + (size_t)i * 8) = o;
}

// ---- MFMA projection, SWAPPED operands: D[feat][node] = Wfrag x Xfrag.
// Each lane ends with 4 consecutive features of ONE node -> contiguous stores.
// Outputs: qh fp16 [n][64], kvh fp16 [n][128] (K|V), sout fp32 [n][64] (skip).
__global__ __launch_bounds__(256) void k_projM(
    const _Float16* __restrict__ xb, const _Float16* __restrict__ wf,
    const float* __restrict__ bq, const float* __restrict__ bk,
    const float* __restrict__ bv, const float* __restrict__ bs,
    _Float16* __restrict__ qh, _Float16* __restrict__ kvh,
    float* __restrict__ sout, int n)
{
  int wave = threadIdx.x >> 6;
  int lane = threadIdx.x & 63;
  int nbase = blockIdx.x * 64 + wave * 16;
  if (nbase >= n) return;

  const int cl = lane & 15;
  const int rq = lane >> 4;

  // B operand = x: B[k][col=node]; lane holds node = nbase+cl, k-chunk rq*8..+8
  int ar = min(nbase + cl, n - 1);
  h8 a0 = *(const h8*)(xb + (size_t)ar * DD + rq * 8);
  h8 a1 = *(const h8*)(xb + (size_t)ar * DD + 32 + rq * 8);

  const int node = nbase + cl;
  const bool nok = (node < n);

  for (int c = 0; c < 16; ++c) {
    const float* bp = (c < 4) ? bq : (c < 8) ? bk : (c < 12) ? bv : bs;
    const int fb = c * 16 + rq * 4;          // global feature base (0..255)
    float4 b4 = *(const float4*)(bp + (fb & 63));
    f32x4 acc; acc[0] = b4.x; acc[1] = b4.y; acc[2] = b4.z; acc[3] = b4.w;
    const _Float16* wp = wf + ((size_t)(c * 2) * 64 + lane) * 8;
    h8 w0 = *(const h8*)(wp);
    h8 w1 = *(const h8*)(wp + 64 * 8);
    acc = __builtin_amdgcn_mfma_f32_16x16x32_f16(w0, a0, acc, 0, 0, 0);
    acc = __builtin_amdgcn_mfma_f32_16x16x32_f16(w1, a1, acc, 0, 0, 0);

    if (nok) {
      if (c < 4) {
        h4 o; o[0] = (_Float16)acc[0]; o[1] = (_Float16)acc[1];
        o[2] = (_Float16)acc[2]; o[3] = (_Float16)acc[3];
        *(h4*)(qh + (size_t)node * DD + fb) = o;              // 8B store
      } else if (c < 12) {
        h4 o; o[0] = (_Float16)acc[0]; o[1] = (_Float16)acc[1];
        o[2] = (_Float16)acc[2]; o[3] = (_Float16)acc[3];
        *(h4*)(kvh + (size_t)node * 128 + (fb - 64)) = o;     // K: 0..63, V: 64..127
      } else {
        *(f32x4*)(sout + (size_t)node * DD + (fb & 63)) = acc; // 16B store
      }
    }
  }
}

// ---- CSR build ----
// 4 edges/thread, int4 loads; pos as ushort (max deg << 65536)
__global__ __launch_bounds__(256) void k_hist(
    const int* __restrict__ dst, int* __restrict__ deg,
    unsigned short* __restrict__ pos, int ecnt)
{
  int e = (blockIdx.x * 256 + threadIdx.x) * 4;
  if (e + 3 < ecnt) {
    int4 d = *(const int4*)(dst + e);
    pos[e]     = (unsigned short)atomicAdd(deg + d.x, 1);
    pos[e + 1] = (unsigned short)atomicAdd(deg + d.y, 1);
    pos[e + 2] = (unsigned short)atomicAdd(deg + d.z, 1);
    pos[e + 3] = (unsigned short)atomicAdd(deg + d.w, 1);
  } else {
    for (; e < ecnt; ++e)
      pos[e] = (unsigned short)atomicAdd(deg + dst[e], 1);
  }
}

// exclusive scan, 1 WG, 4 elems/thread per pass
__global__ __launch_bounds__(1024) void k_scan(
    const int* __restrict__ deg, int* __restrict__ rowptr, int n)
{
  __shared__ int wsum[16];
  int lane = threadIdx.x & 63;
  int wave = threadIdx.x >> 6;
  if (threadIdx.x == 0) rowptr[0] = 0;
  int carry = 0;
  for (int base = 0; base < n; base += 4096) {
    int i = base + threadIdx.x * 4;
    int4 d = make_int4(0, 0, 0, 0);
    if (i + 3 < n) d = *(const int4*)(deg + i);
    else {
      if (i     < n) d.x = deg[i];
      if (i + 1 < n) d.y = deg[i + 1];
      if (i + 2 < n) d.z = deg[i + 2];
    }
    int s1 = d.x, s2 = s1 + d.y, s3 = s2 + d.z, s4 = s3 + d.w;
    int s = s4;
    #pragma unroll
    for (int off = 1; off < 64; off <<= 1) {
      int t = __shfl_up(s, off);
      if (lane >= off) s += t;
    }
    if (lane == 63) wsum[wave] = s;
    __syncthreads();
    if (wave == 0) {
      int ws = (lane < 16) ? wsum[lane] : 0;
      #pragma unroll
      for (int off = 1; off < 16; off <<= 1) {
        int t = __shfl_up(ws, off);
        if (lane >= off) ws += t;
      }
      if (lane < 16) wsum[lane] = ws;
    }
    __syncthreads();
    int excl = carry + ((wave > 0) ? wsum[wave - 1] : 0) + s - s4;
    if (i     < n) rowptr[i + 1] = excl + s1;
    if (i + 1 < n) rowptr[i + 2] = excl + s2;
    if (i + 2 < n) rowptr[i + 3] = excl + s3;
    if (i + 3 < n) rowptr[i + 4] = excl + s4;
    carry += wsum[15];
    __syncthreads();
  }
}

// atomic-free fill using precomputed pos
__global__ __launch_bounds__(256) void k_fill(
    const int* __restrict__ src, const int* __restrict__ dst,
    const int* __restrict__ rowptr, const unsigned short* __restrict__ pos,
    int* __restrict__ adj, int ecnt)
{
  int e = (blockIdx.x * 256 + threadIdx.x) * 4;
  if (e + 3 < ecnt) {
    int4 d = *(const int4*)(dst + e);
    int4 s = *(const int4*)(src + e);
    ushort4 p = *(const ushort4*)(pos + e);
    adj[rowptr[d.x] + p.x] = s.x;
    adj[rowptr[d.y] + p.y] = s.y;
    adj[rowptr[d.z] + p.z] = s.z;
    adj[rowptr[d.w] + p.w] = s.w;
  } else {
    for (; e < ecnt; ++e)
      adj[rowptr[dst[e]] + pos[e]] = src[e];
  }
}

#define H2OF(v, i) __builtin_shufflevector((v), (v), 2*(i), 2*(i)+1)

// ---- one wave per dst node, 8 edges/iter, 8 lanes/edge, fp16 KV gathers.
// adj is zero-padded by 8 so prefetch needs no clamps; 32-bit gather offsets.
// skip S (fp32) read from sskip; MID layers write only fp16 xbnext,
// LAST layer writes only fp32 outp.
template<bool LAST>
__global__ __launch_bounds__(256) void k_node(
    const _Float16* __restrict__ qh, const _Float16* __restrict__ kvh,
    const int* __restrict__ rowptr, const int* __restrict__ adj,
    const float* __restrict__ sskip, float* __restrict__ outp,
    _Float16* __restrict__ xbnext, int n)
{
  int node = (blockIdx.x * blockDim.x + threadIdx.x) >> 6;
  node = __builtin_amdgcn_readfirstlane(node);   // wave-uniform -> SGPR
  int lane = threadIdx.x & 63;
  if (node >= n) return;
  const int g = lane >> 3;   // sub-edge 0..7
  const int t = lane & 7;    // dim-chunk 0..7 (dims 8t..8t+7)

  const h8 q8 = *(const h8*)((const char*)qh + (((unsigned)node << 7) + (t << 4)));
  const h2 qp0 = H2OF(q8, 0), qp1 = H2OF(q8, 1), qp2 = H2OF(q8, 2), qp3 = H2OF(q8, 3);

  const int e0 = rowptr[node], e1 = rowptr[node + 1];
  float m = -INFINITY, denom = 0.f;
  float agg[8] = {0.f, 0.f, 0.f, 0.f, 0.f, 0.f, 0.f, 0.f};

  const char* kvb = (const char*)kvh;
  h8 kP, vP;
  {
    int sP = adj[e0 + g];                        // padded: always in-bounds
    unsigned off = ((unsigned)sP << 8) + ((unsigned)t << 4);
    kP = *(const h8*)(kvb + off);
    vP = *(const h8*)(kvb + off + 128);
  }

  for (int base = e0; base < e1; base += 8) {
    const h8 kc = kP, vc = vP;
    const bool valid = (base + g < e1);
    const int nb2 = base + 8;
    if (nb2 < e1) {                              // prefetch next chunk
      int s2 = adj[nb2 + g];
      unsigned off = ((unsigned)s2 << 8) + ((unsigned)t << 4);
      kP = *(const h8*)(kvb + off);
      vP = *(const h8*)(kvb + off + 128);
    }

#if __has_builtin(__builtin_amdgcn_fdot2)
    float p = __builtin_amdgcn_fdot2(qp0, H2OF(kc, 0), 0.f, false);
    p = __builtin_amdgcn_fdot2(qp1, H2OF(kc, 1), p, false);
    p = __builtin_amdgcn_fdot2(qp2, H2OF(kc, 2), p, false);
    p = __builtin_amdgcn_fdot2(qp3, H2OF(kc, 3), p, false);
#else
    h2 ph = qp0 * H2OF(kc, 0);
    ph = qp1 * H2OF(kc, 1) + ph;
    ph = qp2 * H2OF(kc, 2) + ph;
    ph = qp3 * H2OF(kc, 3) + ph;
    float p = (float)ph.x + (float)ph.y;
#endif
    p += __shfl_xor(p, 1);
    p += __shfl_xor(p, 2);
    p += __shfl_xor(p, 4);
    p *= 0.125f;                       // 1/sqrt(64)
    if (!valid) p = -INFINITY;
    float cm = fmaxf(p, __shfl_xor(p, 8));
    cm = fmaxf(cm, __shfl_xor(cm, 16));
    cm = fmaxf(cm, __shfl_xor(cm, 32));   // wave-uniform chunk max
    if (cm > m) {
      float cc = __expf(m - cm);
      denom *= cc;
      #pragma unroll
      for (int j = 0; j < 8; ++j) agg[j] *= cc;
      m = cm;
    }
    float w = __expf(p - m);
    denom += w;
    #pragma unroll
    for (int j = 0; j < 8; ++j)
      agg[j] = fmaf(w, (float)vc[j], agg[j]);
  }

  denom += __shfl_xor(denom, 8);
  denom += __shfl_xor(denom, 16);
  denom += __shfl_xor(denom, 32);
  #pragma unroll
  for (int j = 0; j < 8; ++j) {
    agg[j] += __shfl_xor(agg[j], 8);
    agg[j] += __shfl_xor(agg[j], 16);
    agg[j] += __shfl_xor(agg[j], 32);
  }

  if (g == 0) {
    float inv = (denom > 0.f) ? (1.0f / denom) : 0.f;
    const float* sp = (const float*)((const char*)sskip +
                      (((unsigned)node << 8) + (t << 5)));
    float4 sa = *(const float4*)(sp);
    float4 sb = *(const float4*)(sp + 4);
    float r[8];
    r[0] = fmaxf(fmaf(agg[0], inv, sa.x), 0.f);
    r[1] = fmaxf(fmaf(agg[1], inv, sa.y), 0.f);
    r[2] = fmaxf(fmaf(agg[2], inv, sa.z), 0.f);
    r[3] = fmaxf(fmaf(agg[3], inv, sa.w), 0.f);
    r[4] = fmaxf(fmaf(agg[4], inv, sb.x), 0.f);
    r[5] = fmaxf(fmaf(agg[5], inv, sb.y), 0.f);
    r[6] = fmaxf(fmaf(agg[6], inv, sb.z), 0.f);
    r[7] = fmaxf(fmaf(agg[7], inv, sb.w), 0.f);
    if (LAST) {
      float* op = (float*)((char*)outp + (((unsigned)node << 8) + (t << 5)));
      *(float4*)(op)     = make_float4(r[0], r[1], r[2], r[3]);
      *(float4*)(op + 4) = make_float4(r[4], r[5], r[6], r[7]);
    } else {
      h8 xh;
      #pragma unroll
      for (int j = 0; j < 8; ++j) xh[j] = (_Float16)r[j];
      *(h8*)((char*)xbnext + (((unsigned)node << 7) + (t << 4))) = xh;
    }
  }
}

// batch is sorted: run-length accumulate per wave, flush on graph change
__global__ __launch_bounds__(64) void k_pool_sum(
    const float* __restrict__ x, const int* __restrict__ batch,
    float* __restrict__ gsum, float* __restrict__ gcnt, int n)
{
  int lane = threadIdx.x;
  int n0 = blockIdx.x * 64;
  if (n0 >= n) return;
  int n1 = min(n0 + 64, n);
  float acc = 0.f;
  int g_prev = batch[n0];
  int run = 0;
  for (int nn = n0; nn < n1; ++nn) {
    int g = batch[nn];
    if (g != g_prev) {
      atomicAdd(gsum + (size_t)g_prev * DD + lane, acc);
      if (lane == 0) atomicAdd(gcnt + g_prev, (float)run);
      acc = 0.f; run = 0; g_prev = g;
    }
    acc += x[(size_t)nn * DD + lane];
    run++;
  }
  atomicAdd(gsum + (size_t)g_prev * DD + lane, acc);
  if (lane == 0) atomicAdd(gcnt + g_prev, (float)run);
}

__global__ __launch_bounds__(256) void k_pool_div(
    const float* __restrict__ gsum, const float* __restrict__ gcnt,
    float* __restrict__ emb, int gtot)
{
  int gid = blockIdx.x * blockDim.x + threadIdx.x;
  if (gid >= gtot * DD) return;
  int g = gid >> 6;
  emb[gid] = gsum[gid] / fmaxf(gcnt[g], 1.0f);
}

extern "C" void kernel_launch(void* const* d_in, const int* in_sizes, int n_in,
                              void* d_out, int out_size, void* d_ws, size_t ws_size,
                              hipStream_t stream)
{
  const float* x_in  = (const float*)d_in[0];
  const int*   ei    = (const int*)  d_in[1];
  const int*   batch = (const int*)  d_in[2];
  const float* Wq = (const float*)d_in[3];
  const float* bq = (const float*)d_in[4];
  const float* Wk = (const float*)d_in[5];
  const float* bk = (const float*)d_in[6];
  const float* Wv = (const float*)d_in[7];
  const float* bv = (const float*)d_in[8];
  const float* Ws = (const float*)d_in[9];
  const float* bs = (const float*)d_in[10];

  const int nd     = in_sizes[0];             // N*D
  const int n      = nd / DD;                 // N
  const int ecnt   = in_sizes[1] / 2;         // E
  const int layers = in_sizes[3] / (DD * DD); // L
  const int gtot   = (out_size - nd) / DD;    // G

  const int* src = ei;
  const int* dst = ei + ecnt;

  // workspace layout (16B-aligned blocks first)
  char* cur = (char*)d_ws;
  float*     P0  = (float*)cur;     cur += (size_t)nd * 4;        // fp32 skip S
  _Float16*  XB  = (_Float16*)cur;  cur += (size_t)nd * 2;        // fp16 x
  _Float16*  QH  = (_Float16*)cur;  cur += (size_t)nd * 2;        // fp16 Q
  _Float16*  KVH = (_Float16*)cur;  cur += (size_t)nd * 4;        // fp16 K|V
  _Float16*  WF  = (_Float16*)cur;  cur += (size_t)layers * 16384 * 2; // W frags
  int* rowptr = (int*)cur;          cur += (size_t)(n + 4) * 4;
  int* deg    = (int*)cur;          cur += (size_t)n * 4;
  int* adj    = (int*)cur;          cur += (size_t)(ecnt + 8) * 4; // +8 pad
  unsigned short* pos = (unsigned short*)cur; cur += (size_t)ecnt * 2;
  float* gsum = (float*)cur;        cur += (size_t)gtot * DD * 4;
  float* gcnt = (float*)cur;

  float* out = (float*)d_out;

  // ---- one-time prep: W fragments, x fp16, CSR ----
  k_wconv<<<layers * 32, 64, 0, stream>>>(Wq, Wk, Wv, Ws, WF);
  k_xconv<<<(n * 8 + 255) / 256, 256, 0, stream>>>(x_in, XB, n * 8);
  hipMemsetAsync(deg, 0, (size_t)n * 4, stream);
  hipMemsetAsync(adj + ecnt, 0, 8 * 4, stream);   // zero the pad
  const int eb4 = (ecnt + 1023) / 1024;
  k_hist<<<eb4, 256, 0, stream>>>(dst, deg, pos, ecnt);
  k_scan<<<1, 1024, 0, stream>>>(deg, rowptr, n);
  k_fill<<<eb4, 256, 0, stream>>>(src, dst, rowptr, pos, adj, ecnt);

  const int pj = (n + 63) / 64;
  const int nb = (n * 64 + 255) / 256;

  for (int l = 0; l < layers; ++l) {
    const size_t bo = (size_t)l * DD;
    k_projM<<<pj, 256, 0, stream>>>(XB, WF + (size_t)l * 16384,
                                    bq + bo, bk + bo, bv + bo, bs + bo,
                                    QH, KVH, P0, n);
    if (l == layers - 1)
      k_node<true><<<nb, 256, 0, stream>>>(QH, KVH, rowptr, adj, P0, out, XB, n);
    else
      k_node<false><<<nb, 256, 0, stream>>>(QH, KVH, rowptr, adj, P0, out, XB, n);
  }

  hipMemsetAsync(gsum, 0, (size_t)gtot * DD * 4, stream);
  hipMemsetAsync(gcnt, 0, (size_t)gtot * 4, stream);
  const int pbk = (n + 63) / 64;
  k_pool_sum<<<pbk, 64, 0, stream>>>(out, batch, gsum, gcnt, n);
  const int fb = (gtot * DD + 255) / 256;
  k_pool_div<<<fb, 256, 0, stream>>>(gsum, gcnt, out + (size_t)nd, gtot);
}

// Round 7
// 385.177 us; speedup vs baseline: 1.0924x; 1.0924x over previous
//
#include <hip/hip_runtime.h>
#include <math.h>

#define DD 64   // feature dim

typedef _Float16 h2 __attribute__((ext_vector_type(2)));
typedef _Float16 h4 __attribute__((ext_vector_type(4)));
typedef _Float16 h8 __attribute__((ext_vector_type(8)));
typedef float f32x4 __attribute__((ext_vector_type(4)));

// ---- W -> MFMA A-fragment pre-shuffle (fp16), all layers at once ----
// wf layout: [layer][colTile c:16][kstep s:2][lane:64][j:8]
// element = W[k = s*32 + (lane>>4)*8 + j][feat = c*16 + (lane&15)]
__global__ __launch_bounds__(64) void k_wconv(
    const float* __restrict__ Wq, const float* __restrict__ Wk,
    const float* __restrict__ Wv, const float* __restrict__ Ws,
    _Float16* __restrict__ wf)
{
  int bid = blockIdx.x;          // layer*32 + c*2 + s
  int layer = bid >> 5;
  int c = (bid >> 1) & 15;
  int s = bid & 1;
  int lane = threadIdx.x;
  int col = c * 16 + (lane & 15);
  int mi = col >> 6;
  const float* W = (mi == 0 ? Wq : mi == 1 ? Wk : mi == 2 ? Wv : Ws)
                   + (size_t)layer * DD * DD;
  int colw = col & 63;
  _Float16* o = wf + ((((size_t)(layer * 16 + c)) * 2 + s) * 64 + lane) * 8;
  #pragma unroll
  for (int j = 0; j < 8; ++j) {
    int k = s * 32 + (lane >> 4) * 8 + j;
    o[j] = (_Float16)W[k * DD + colw];
  }
}

// fp32 -> fp16 convert (8 elems/thread)
__global__ __launch_bounds__(256) void k_xconv(
    const float* __restrict__ x, _Float16* __restrict__ xb, int total8)
{
  int i = blockIdx.x * 256 + threadIdx.x;
  if (i >= total8) return;
  float4 a = ((const float4*)x)[i * 2];
  float4 b = ((const float4*)x)[i * 2 + 1];
  h8 o;
  o[0] = (_Float16)a.x; o[1] = (_Float16)a.y; o[2] = (_Float16)a.z; o[3] = (_Float16)a.w;
  o[4] = (_Float16)b.x; o[5] = (_Float16)b.y; o[6] = (_Float16)b.z; o[7] = (_Float16)b.w;
  *(h8*)(xb + (size_t)i * 8) = o;
}

// ---- MFMA projection, swapped operands: lane holds 4 consecutive features of
// one node. Results staged per-wave in LDS (bank-padded), then written with
// fully-coalesced 16B stores.
// Outputs: qh fp16 [n][64], kvh fp16 [n][128] (K|V), sout fp32 [n][64] (skip).
#define LH_STRIDE 200   // halves per node row (192 used + 8 pad) = 400B
#define LF_STRIDE 68    // floats per node row (64 used + 4 pad)  = 272B
#define WAVE_LDS  (16 * 400 + 16 * 272)   // 10752B

__global__ __launch_bounds__(256) void k_projM(
    const _Float16* __restrict__ xb, const _Float16* __restrict__ wf,
    const float* __restrict__ bq, const float* __restrict__ bk,
    const float* __restrict__ bv, const float* __restrict__ bs,
    _Float16* __restrict__ qh, _Float16* __restrict__ kvh,
    float* __restrict__ sout, int n)
{
  __shared__ __align__(16) char lds[4 * WAVE_LDS];
  int wave = threadIdx.x >> 6;
  int lane = threadIdx.x & 63;
  int nbase = blockIdx.x * 64 + wave * 16;
  if (nbase >= n) return;

  char* wbase = lds + wave * WAVE_LDS;
  _Float16* lh = (_Float16*)wbase;                 // [16][LH_STRIDE]
  float*    lf = (float*)(wbase + 16 * 400);       // [16][LF_STRIDE]

  const int cl = lane & 15;
  const int rq = lane >> 4;

  // B operand = x: lane holds node = nbase+cl, k-chunk rq*8..+8
  int ar = min(nbase + cl, n - 1);
  h8 a0 = *(const h8*)(xb + (size_t)ar * DD + rq * 8);
  h8 a1 = *(const h8*)(xb + (size_t)ar * DD + 32 + rq * 8);

  #pragma unroll
  for (int c = 0; c < 16; ++c) {
    const float* bp = (c < 4) ? bq : (c < 8) ? bk : (c < 12) ? bv : bs;
    const int fb = c * 16 + rq * 4;          // global feature base (0..255)
    float4 b4 = *(const float4*)(bp + (fb & 63));
    f32x4 acc; acc[0] = b4.x; acc[1] = b4.y; acc[2] = b4.z; acc[3] = b4.w;
    const _Float16* wp = wf + ((size_t)(c * 2) * 64 + lane) * 8;
    h8 w0 = *(const h8*)(wp);
    h8 w1 = *(const h8*)(wp + 64 * 8);
    acc = __builtin_amdgcn_mfma_f32_16x16x32_f16(w0, a0, acc, 0, 0, 0);
    acc = __builtin_amdgcn_mfma_f32_16x16x32_f16(w1, a1, acc, 0, 0, 0);

    if (c < 12) {
      h4 o; o[0] = (_Float16)acc[0]; o[1] = (_Float16)acc[1];
      o[2] = (_Float16)acc[2]; o[3] = (_Float16)acc[3];
      *(h4*)(lh + cl * LH_STRIDE + fb) = o;             // fb in [0,192)
    } else {
      *(f32x4*)(lf + cl * LF_STRIDE + (fb - 192)) = acc;
    }
  }
  // wave-private LDS: no barrier needed; compiler inserts lgkmcnt waits.

  // QH: 16 nodes x 128B = 2 iters of 64 lanes x 16B
  #pragma unroll
  for (int i = 0; i < 2; ++i) {
    int chunk = i * 64 + lane;          // [0,128)
    int nd = chunk >> 3, co = chunk & 7;
    h8 v = *(const h8*)(lh + nd * LH_STRIDE + co * 8);
    if (nbase + nd < n)
      *(h8*)(qh + (size_t)(nbase + nd) * DD + co * 8) = v;
  }
  // KVH: 16 nodes x 256B = 4 iters (halves 64..191)
  #pragma unroll
  for (int i = 0; i < 4; ++i) {
    int chunk = i * 64 + lane;          // [0,256)
    int nd = chunk >> 4, co = chunk & 15;
    h8 v = *(const h8*)(lh + nd * LH_STRIDE + 64 + co * 8);
    if (nbase + nd < n)
      *(h8*)(kvh + (size_t)(nbase + nd) * 128 + co * 8) = v;
  }
  // S: 16 nodes x 256B fp32 = 4 iters
  #pragma unroll
  for (int i = 0; i < 4; ++i) {
    int chunk = i * 64 + lane;
    int nd = chunk >> 4, co = chunk & 15;
    f32x4 v = *(const f32x4*)(lf + nd * LF_STRIDE + co * 4);
    if (nbase + nd < n)
      *(f32x4*)(sout + (size_t)(nbase + nd) * DD + co * 4) = v;
  }
}

// ---- CSR build ----
__global__ __launch_bounds__(256) void k_hist(
    const int* __restrict__ dst, int* __restrict__ deg,
    unsigned short* __restrict__ pos, int ecnt)
{
  int e = (blockIdx.x * 256 + threadIdx.x) * 4;
  if (e + 3 < ecnt) {
    int4 d = *(const int4*)(dst + e);
    pos[e]     = (unsigned short)atomicAdd(deg + d.x, 1);
    pos[e + 1] = (unsigned short)atomicAdd(deg + d.y, 1);
    pos[e + 2] = (unsigned short)atomicAdd(deg + d.z, 1);
    pos[e + 3] = (unsigned short)atomicAdd(deg + d.w, 1);
  } else {
    for (; e < ecnt; ++e)
      pos[e] = (unsigned short)atomicAdd(deg + dst[e], 1);
  }
}

// exclusive scan, 1 WG, 4 elems/thread per pass
__global__ __launch_bounds__(1024) void k_scan(
    const int* __restrict__ deg, int* __restrict__ rowptr, int n)
{
  __shared__ int wsum[16];
  int lane = threadIdx.x & 63;
  int wave = threadIdx.x >> 6;
  if (threadIdx.x == 0) rowptr[0] = 0;
  int carry = 0;
  for (int base = 0; base < n; base += 4096) {
    int i = base + threadIdx.x * 4;
    int4 d = make_int4(0, 0, 0, 0);
    if (i + 3 < n) d = *(const int4*)(deg + i);
    else {
      if (i     < n) d.x = deg[i];
      if (i + 1 < n) d.y = deg[i + 1];
      if (i + 2 < n) d.z = deg[i + 2];
    }
    int s1 = d.x, s2 = s1 + d.y, s3 = s2 + d.z, s4 = s3 + d.w;
    int s = s4;
    #pragma unroll
    for (int off = 1; off < 64; off <<= 1) {
      int t = __shfl_up(s, off);
      if (lane >= off) s += t;
    }
    if (lane == 63) wsum[wave] = s;
    __syncthreads();
    if (wave == 0) {
      int ws = (lane < 16) ? wsum[lane] : 0;
      #pragma unroll
      for (int off = 1; off < 16; off <<= 1) {
        int t = __shfl_up(ws, off);
        if (lane >= off) ws += t;
      }
      if (lane < 16) wsum[lane] = ws;
    }
    __syncthreads();
    int excl = carry + ((wave > 0) ? wsum[wave - 1] : 0) + s - s4;
    if (i     < n) rowptr[i + 1] = excl + s1;
    if (i + 1 < n) rowptr[i + 2] = excl + s2;
    if (i + 2 < n) rowptr[i + 3] = excl + s3;
    if (i + 3 < n) rowptr[i + 4] = excl + s4;
    carry += wsum[15];
    __syncthreads();
  }
}

// atomic-free fill using precomputed pos
__global__ __launch_bounds__(256) void k_fill(
    const int* __restrict__ src, const int* __restrict__ dst,
    const int* __restrict__ rowptr, const unsigned short* __restrict__ pos,
    int* __restrict__ adj, int ecnt)
{
  int e = (blockIdx.x * 256 + threadIdx.x) * 4;
  if (e + 3 < ecnt) {
    int4 d = *(const int4*)(dst + e);
    int4 s = *(const int4*)(src + e);
    ushort4 p = *(const ushort4*)(pos + e);
    adj[rowptr[d.x] + p.x] = s.x;
    adj[rowptr[d.y] + p.y] = s.y;
    adj[rowptr[d.z] + p.z] = s.z;
    adj[rowptr[d.w] + p.w] = s.w;
  } else {
    for (; e < ecnt; ++e)
      adj[rowptr[dst[e]] + pos[e]] = src[e];
  }
}

#define H2OF(v, i) __builtin_shufflevector((v), (v), 2*(i), 2*(i)+1)

// ---- one wave per dst node, 8 edges/iter, 8 lanes/edge.
// PER-GROUP online softmax: each 8-lane group keeps private (m, denom, agg);
// groups merge once at the end. No cross-group sync in the inner loop.
template<bool LAST>
__global__ __launch_bounds__(256) void k_node(
    const _Float16* __restrict__ qh, const _Float16* __restrict__ kvh,
    const int* __restrict__ rowptr, const int* __restrict__ adj,
    const float* __restrict__ sskip, float* __restrict__ outp,
    _Float16* __restrict__ xbnext, int n)
{
  int node = (blockIdx.x * blockDim.x + threadIdx.x) >> 6;
  node = __builtin_amdgcn_readfirstlane(node);   // wave-uniform -> SGPR
  int lane = threadIdx.x & 63;
  if (node >= n) return;
  const int g = lane >> 3;   // sub-edge 0..7
  const int t = lane & 7;    // dim-chunk 0..7 (dims 8t..8t+7)

  const h8 q8 = *(const h8*)((const char*)qh + (((unsigned)node << 7) + (t << 4)));
  const h2 qp0 = H2OF(q8, 0), qp1 = H2OF(q8, 1), qp2 = H2OF(q8, 2), qp3 = H2OF(q8, 3);

  const int e0 = rowptr[node], e1 = rowptr[node + 1];
  float mg = -1e30f, den = 0.f;
  float agg[8] = {0.f, 0.f, 0.f, 0.f, 0.f, 0.f, 0.f, 0.f};

  const char* kvb = (const char*)kvh;
  h8 kP, vP;
  {
    int sP = adj[e0 + g];                        // padded: always in-bounds
    unsigned off = ((unsigned)sP << 8) + ((unsigned)t << 4);
    kP = *(const h8*)(kvb + off);
    vP = *(const h8*)(kvb + off + 128);
  }

  for (int base = e0; base < e1; base += 8) {
    const h8 kc = kP, vc = vP;
    const bool valid = (base + g < e1);
    const int nb2 = base + 8;
    if (nb2 < e1) {                              // prefetch next chunk
      int s2 = adj[nb2 + g];
      unsigned off = ((unsigned)s2 << 8) + ((unsigned)t << 4);
      kP = *(const h8*)(kvb + off);
      vP = *(const h8*)(kvb + off + 128);
    }

#if __has_builtin(__builtin_amdgcn_fdot2)
    float p = __builtin_amdgcn_fdot2(qp0, H2OF(kc, 0), 0.f, false);
    p = __builtin_amdgcn_fdot2(qp1, H2OF(kc, 1), p, false);
    p = __builtin_amdgcn_fdot2(qp2, H2OF(kc, 2), p, false);
    p = __builtin_amdgcn_fdot2(qp3, H2OF(kc, 3), p, false);
#else
    h2 ph = qp0 * H2OF(kc, 0);
    ph = qp1 * H2OF(kc, 1) + ph;
    ph = qp2 * H2OF(kc, 2) + ph;
    ph = qp3 * H2OF(kc, 3) + ph;
    float p = (float)ph.x + (float)ph.y;
#endif
    p += __shfl_xor(p, 1);
    p += __shfl_xor(p, 2);
    p += __shfl_xor(p, 4);     // p replicated within the 8-lane group
    p *= 0.125f;               // 1/sqrt(64)

    if (valid && p > mg) {     // group-uniform branch, rare after warmup
      float c = __expf(mg - p);   // first time: exp(-1e30-p) -> 0
      den *= c;
      #pragma unroll
      for (int j = 0; j < 8; ++j) agg[j] *= c;
      mg = p;
    }
    float w = valid ? __expf(p - mg) : 0.f;
    den += w;
    #pragma unroll
    for (int j = 0; j < 8; ++j)
      agg[j] = fmaf(w, (float)vc[j], agg[j]);
  }

  // merge the 8 groups
  float M = mg;
  M = fmaxf(M, __shfl_xor(M, 8));
  M = fmaxf(M, __shfl_xor(M, 16));
  M = fmaxf(M, __shfl_xor(M, 32));
  float f = __expf(mg - M);     // empty group: exp(-1e30-M) -> 0 (or 1 if all empty)
  den *= f;
  den += __shfl_xor(den, 8);
  den += __shfl_xor(den, 16);
  den += __shfl_xor(den, 32);
  #pragma unroll
  for (int j = 0; j < 8; ++j) {
    agg[j] *= f;
    agg[j] += __shfl_xor(agg[j], 8);
    agg[j] += __shfl_xor(agg[j], 16);
    agg[j] += __shfl_xor(agg[j], 32);
  }

  if (g == 0) {
    float inv = (den > 0.f) ? (1.0f / den) : 0.f;
    const float* sp = (const float*)((const char*)sskip +
                      (((unsigned)node << 8) + (t << 5)));
    float4 sa = *(const float4*)(sp);
    float4 sb = *(const float4*)(sp + 4);
    float r[8];
    r[0] = fmaxf(fmaf(agg[0], inv, sa.x), 0.f);
    r[1] = fmaxf(fmaf(agg[1], inv, sa.y), 0.f);
    r[2] = fmaxf(fmaf(agg[2], inv, sa.z), 0.f);
    r[3] = fmaxf(fmaf(agg[3], inv, sa.w), 0.f);
    r[4] = fmaxf(fmaf(agg[4], inv, sb.x), 0.f);
    r[5] = fmaxf(fmaf(agg[5], inv, sb.y), 0.f);
    r[6] = fmaxf(fmaf(agg[6], inv, sb.z), 0.f);
    r[7] = fmaxf(fmaf(agg[7], inv, sb.w), 0.f);
    if (LAST) {
      float* op = (float*)((char*)outp + (((unsigned)node << 8) + (t << 5)));
      *(float4*)(op)     = make_float4(r[0], r[1], r[2], r[3]);
      *(float4*)(op + 4) = make_float4(r[4], r[5], r[6], r[7]);
    } else {
      h8 xh;
      #pragma unroll
      for (int j = 0; j < 8; ++j) xh[j] = (_Float16)r[j];
      *(h8*)((char*)xbnext + (((unsigned)node << 7) + (t << 4))) = xh;
    }
  }
}

// batch is sorted: run-length accumulate per wave, flush on graph change
__global__ __launch_bounds__(64) void k_pool_sum(
    const float* __restrict__ x, const int* __restrict__ batch,
    float* __restrict__ gsum, float* __restrict__ gcnt, int n)
{
  int lane = threadIdx.x;
  int n0 = blockIdx.x * 64;
  if (n0 >= n) return;
  int n1 = min(n0 + 64, n);
  float acc = 0.f;
  int g_prev = batch[n0];
  int run = 0;
  for (int nn = n0; nn < n1; ++nn) {
    int g = batch[nn];
    if (g != g_prev) {
      atomicAdd(gsum + (size_t)g_prev * DD + lane, acc);
      if (lane == 0) atomicAdd(gcnt + g_prev, (float)run);
      acc = 0.f; run = 0; g_prev = g;
    }
    acc += x[(size_t)nn * DD + lane];
    run++;
  }
  atomicAdd(gsum + (size_t)g_prev * DD + lane, acc);
  if (lane == 0) atomicAdd(gcnt + g_prev, (float)run);
}

__global__ __launch_bounds__(256) void k_pool_div(
    const float* __restrict__ gsum, const float* __restrict__ gcnt,
    float* __restrict__ emb, int gtot)
{
  int gid = blockIdx.x * blockDim.x + threadIdx.x;
  if (gid >= gtot * DD) return;
  int g = gid >> 6;
  emb[gid] = gsum[gid] / fmaxf(gcnt[g], 1.0f);
}

extern "C" void kernel_launch(void* const* d_in, const int* in_sizes, int n_in,
                              void* d_out, int out_size, void* d_ws, size_t ws_size,
                              hipStream_t stream)
{
  const float* x_in  = (const float*)d_in[0];
  const int*   ei    = (const int*)  d_in[1];
  const int*   batch = (const int*)  d_in[2];
  const float* Wq = (const float*)d_in[3];
  const float* bq = (const float*)d_in[4];
  const float* Wk = (const float*)d_in[5];
  const float* bk = (const float*)d_in[6];
  const float* Wv = (const float*)d_in[7];
  const float* bv = (const float*)d_in[8];
  const float* Ws = (const float*)d_in[9];
  const float* bs = (const float*)d_in[10];

  const int nd     = in_sizes[0];             // N*D
  const int n      = nd / DD;                 // N
  const int ecnt   = in_sizes[1] / 2;         // E
  const int layers = in_sizes[3] / (DD * DD); // L
  const int gtot   = (out_size - nd) / DD;    // G

  const int* src = ei;
  const int* dst = ei + ecnt;

  // workspace layout (16B-aligned blocks first); adj-pad and deg adjacent so
  // one memset covers both.
  char* cur = (char*)d_ws;
  float*     P0  = (float*)cur;     cur += (size_t)nd * 4;        // fp32 skip S
  _Float16*  XB  = (_Float16*)cur;  cur += (size_t)nd * 2;        // fp16 x
  _Float16*  QH  = (_Float16*)cur;  cur += (size_t)nd * 2;        // fp16 Q
  _Float16*  KVH = (_Float16*)cur;  cur += (size_t)nd * 4;        // fp16 K|V
  _Float16*  WF  = (_Float16*)cur;  cur += (size_t)layers * 16384 * 2; // W frags
  int* rowptr = (int*)cur;          cur += (size_t)(n + 4) * 4;
  int* adj    = (int*)cur;          cur += (size_t)(ecnt + 8) * 4; // +8 pad
  int* deg    = (int*)cur;          cur += (size_t)n * 4;          // right after pad
  unsigned short* pos = (unsigned short*)cur; cur += (size_t)ecnt * 2;
  float* gsum = (float*)cur;        cur += (size_t)gtot * DD * 4;  // gcnt follows
  float* gcnt = (float*)cur;

  float* out = (float*)d_out;

  // ---- one-time prep: W fragments, x fp16, CSR ----
  k_wconv<<<layers * 32, 64, 0, stream>>>(Wq, Wk, Wv, Ws, WF);
  k_xconv<<<(n * 8 + 255) / 256, 256, 0, stream>>>(x_in, XB, n * 8);
  hipMemsetAsync(adj + ecnt, 0, (size_t)(8 + n) * 4, stream);  // pad + deg
  const int eb4 = (ecnt + 1023) / 1024;
  k_hist<<<eb4, 256, 0, stream>>>(dst, deg, pos, ecnt);
  k_scan<<<1, 1024, 0, stream>>>(deg, rowptr, n);
  k_fill<<<eb4, 256, 0, stream>>>(src, dst, rowptr, pos, adj, ecnt);

  const int pj = (n + 63) / 64;
  const int nb = (n * 64 + 255) / 256;

  for (int l = 0; l < layers; ++l) {
    const size_t bo = (size_t)l * DD;
    k_projM<<<pj, 256, 0, stream>>>(XB, WF + (size_t)l * 16384,
                                    bq + bo, bk + bo, bv + bo, bs + bo,
                                    QH, KVH, P0, n);
    if (l == layers - 1)
      k_node<true><<<nb, 256, 0, stream>>>(QH, KVH, rowptr, adj, P0, out, XB, n);
    else
      k_node<false><<<nb, 256, 0, stream>>>(QH, KVH, rowptr, adj, P0, out, XB, n);
  }

  hipMemsetAsync(gsum, 0, (size_t)(gtot * DD + gtot) * 4, stream);  // gsum+gcnt
  const int pbk = (n + 63) / 64;
  k_pool_sum<<<pbk, 64, 0, stream>>>(out, batch, gsum, gcnt, n);
  const int fb = (gtot * DD + 255) / 256;
  k_pool_div<<<fb, 256, 0, stream>>>(gsum, gcnt, out + (size_t)nd, gtot);
}

// Round 8
// 350.709 us; speedup vs baseline: 1.1998x; 1.0983x over previous
//
#include <hip/hip_runtime.h>
#include <math.h>

#define DD 64   // feature dim

typedef _Float16 h2 __attribute__((ext_vector_type(2)));
typedef _Float16 h4 __attribute__((ext_vector_type(4)));
typedef _Float16 h8 __attribute__((ext_vector_type(8)));
typedef float f32x4 __attribute__((ext_vector_type(4)));

// ---- W -> MFMA A-fragment pre-shuffle (fp16), all layers at once ----
__global__ __launch_bounds__(64) void k_wconv(
    const float* __restrict__ Wq, const float* __restrict__ Wk,
    const float* __restrict__ Wv, const float* __restrict__ Ws,
    _Float16* __restrict__ wf)
{
  int bid = blockIdx.x;          // layer*32 + c*2 + s
  int layer = bid >> 5;
  int c = (bid >> 1) & 15;
  int s = bid & 1;
  int lane = threadIdx.x;
  int col = c * 16 + (lane & 15);
  int mi = col >> 6;
  const float* W = (mi == 0 ? Wq : mi == 1 ? Wk : mi == 2 ? Wv : Ws)
                   + (size_t)layer * DD * DD;
  int colw = col & 63;
  _Float16* o = wf + ((((size_t)(layer * 16 + c)) * 2 + s) * 64 + lane) * 8;
  #pragma unroll
  for (int j = 0; j < 8; ++j) {
    int k = s * 32 + (lane >> 4) * 8 + j;
    o[j] = (_Float16)W[k * DD + colw];
  }
}

// fp32 -> fp16 convert (8 elems/thread)
__global__ __launch_bounds__(256) void k_xconv(
    const float* __restrict__ x, _Float16* __restrict__ xb, int total8)
{
  int i = blockIdx.x * 256 + threadIdx.x;
  if (i >= total8) return;
  float4 a = ((const float4*)x)[i * 2];
  float4 b = ((const float4*)x)[i * 2 + 1];
  h8 o;
  o[0] = (_Float16)a.x; o[1] = (_Float16)a.y; o[2] = (_Float16)a.z; o[3] = (_Float16)a.w;
  o[4] = (_Float16)b.x; o[5] = (_Float16)b.y; o[6] = (_Float16)b.z; o[7] = (_Float16)b.w;
  *(h8*)(xb + (size_t)i * 8) = o;
}

// ---- MFMA projection, swapped operands + per-wave LDS staging ----
#define LH_STRIDE 200   // halves per node row (192 used + 8 pad) = 400B
#define LF_STRIDE 68    // floats per node row (64 used + 4 pad)  = 272B
#define WAVE_LDS  (16 * 400 + 16 * 272)   // 10752B

__global__ __launch_bounds__(256) void k_projM(
    const _Float16* __restrict__ xb, const _Float16* __restrict__ wf,
    const float* __restrict__ bq, const float* __restrict__ bk,
    const float* __restrict__ bv, const float* __restrict__ bs,
    _Float16* __restrict__ qh, _Float16* __restrict__ kvh,
    float* __restrict__ sout, int n)
{
  __shared__ __align__(16) char lds[4 * WAVE_LDS];
  int wave = threadIdx.x >> 6;
  int lane = threadIdx.x & 63;
  int nbase = blockIdx.x * 64 + wave * 16;
  if (nbase >= n) return;

  char* wbase = lds + wave * WAVE_LDS;
  _Float16* lh = (_Float16*)wbase;                 // [16][LH_STRIDE]
  float*    lf = (float*)(wbase + 16 * 400);       // [16][LF_STRIDE]

  const int cl = lane & 15;
  const int rq = lane >> 4;

  int ar = min(nbase + cl, n - 1);
  h8 a0 = *(const h8*)(xb + (size_t)ar * DD + rq * 8);
  h8 a1 = *(const h8*)(xb + (size_t)ar * DD + 32 + rq * 8);

  #pragma unroll
  for (int c = 0; c < 16; ++c) {
    const float* bp = (c < 4) ? bq : (c < 8) ? bk : (c < 12) ? bv : bs;
    const int fb = c * 16 + rq * 4;          // global feature base (0..255)
    float4 b4 = *(const float4*)(bp + (fb & 63));
    f32x4 acc; acc[0] = b4.x; acc[1] = b4.y; acc[2] = b4.z; acc[3] = b4.w;
    const _Float16* wp = wf + ((size_t)(c * 2) * 64 + lane) * 8;
    h8 w0 = *(const h8*)(wp);
    h8 w1 = *(const h8*)(wp + 64 * 8);
    acc = __builtin_amdgcn_mfma_f32_16x16x32_f16(w0, a0, acc, 0, 0, 0);
    acc = __builtin_amdgcn_mfma_f32_16x16x32_f16(w1, a1, acc, 0, 0, 0);

    if (c < 12) {
      h4 o; o[0] = (_Float16)acc[0]; o[1] = (_Float16)acc[1];
      o[2] = (_Float16)acc[2]; o[3] = (_Float16)acc[3];
      *(h4*)(lh + cl * LH_STRIDE + fb) = o;
    } else {
      *(f32x4*)(lf + cl * LF_STRIDE + (fb - 192)) = acc;
    }
  }

  // QH: 16 nodes x 128B
  #pragma unroll
  for (int i = 0; i < 2; ++i) {
    int chunk = i * 64 + lane;
    int nd = chunk >> 3, co = chunk & 7;
    h8 v = *(const h8*)(lh + nd * LH_STRIDE + co * 8);
    if (nbase + nd < n)
      *(h8*)(qh + (size_t)(nbase + nd) * DD + co * 8) = v;
  }
  // KVH: 16 nodes x 256B
  #pragma unroll
  for (int i = 0; i < 4; ++i) {
    int chunk = i * 64 + lane;
    int nd = chunk >> 4, co = chunk & 15;
    h8 v = *(const h8*)(lh + nd * LH_STRIDE + 64 + co * 8);
    if (nbase + nd < n)
      *(h8*)(kvh + (size_t)(nbase + nd) * 128 + co * 8) = v;
  }
  // S: 16 nodes x 256B fp32
  #pragma unroll
  for (int i = 0; i < 4; ++i) {
    int chunk = i * 64 + lane;
    int nd = chunk >> 4, co = chunk & 15;
    f32x4 v = *(const f32x4*)(lf + nd * LF_STRIDE + co * 4);
    if (nbase + nd < n)
      *(f32x4*)(sout + (size_t)(nbase + nd) * DD + co * 4) = v;
  }
}

// ---- CSR build ----
__global__ __launch_bounds__(256) void k_hist(
    const int* __restrict__ dst, int* __restrict__ deg,
    unsigned short* __restrict__ pos, int ecnt)
{
  int e = (blockIdx.x * 256 + threadIdx.x) * 4;
  if (e + 3 < ecnt) {
    int4 d = *(const int4*)(dst + e);
    pos[e]     = (unsigned short)atomicAdd(deg + d.x, 1);
    pos[e + 1] = (unsigned short)atomicAdd(deg + d.y, 1);
    pos[e + 2] = (unsigned short)atomicAdd(deg + d.z, 1);
    pos[e + 3] = (unsigned short)atomicAdd(deg + d.w, 1);
  } else {
    for (; e < ecnt; ++e)
      pos[e] = (unsigned short)atomicAdd(deg + dst[e], 1);
  }
}

// ---- parallel scan pass A: block-local scan + degree histogram (fused) ----
__global__ __launch_bounds__(1024) void k_scanA(
    const int* __restrict__ deg, int* __restrict__ rowptr,
    int* __restrict__ btot, int* __restrict__ dbins, int n)
{
  __shared__ int wsum[16];
  __shared__ int lbin[256];
  int tid = threadIdx.x;
  int lane = tid & 63, wave = tid >> 6;
  if (tid < 256) lbin[tid] = 0;
  __syncthreads();
  int i = blockIdx.x * 4096 + tid * 4;
  int4 d = make_int4(0, 0, 0, 0);
  if (i + 3 < n) d = *(const int4*)(deg + i);
  else {
    if (i     < n) d.x = deg[i];
    if (i + 1 < n) d.y = deg[i + 1];
    if (i + 2 < n) d.z = deg[i + 2];
  }
  if (i     < n) atomicAdd(&lbin[min(d.x, 255)], 1);
  if (i + 1 < n) atomicAdd(&lbin[min(d.y, 255)], 1);
  if (i + 2 < n) atomicAdd(&lbin[min(d.z, 255)], 1);
  if (i + 3 < n) atomicAdd(&lbin[min(d.w, 255)], 1);

  int s1 = d.x, s2 = s1 + d.y, s3 = s2 + d.z, s4 = s3 + d.w;
  int s = s4;
  #pragma unroll
  for (int off = 1; off < 64; off <<= 1) {
    int t = __shfl_up(s, off);
    if (lane >= off) s += t;
  }
  if (lane == 63) wsum[wave] = s;
  __syncthreads();
  if (wave == 0) {
    int ws = (lane < 16) ? wsum[lane] : 0;
    #pragma unroll
    for (int off = 1; off < 16; off <<= 1) {
      int t = __shfl_up(ws, off);
      if (lane >= off) ws += t;
    }
    if (lane < 16) wsum[lane] = ws;
  }
  __syncthreads();
  int excl = ((wave > 0) ? wsum[wave - 1] : 0) + s - s4;
  if (i     < n) rowptr[i + 1] = excl + s1;
  if (i + 1 < n) rowptr[i + 2] = excl + s2;
  if (i + 2 < n) rowptr[i + 3] = excl + s3;
  if (i + 3 < n) rowptr[i + 4] = excl + s4;
  if (tid == 0) {
    if (blockIdx.x == 0) rowptr[0] = 0;
    btot[blockIdx.x] = wsum[15];
  }
  if (tid < 256 && lbin[tid]) atomicAdd(&dbins[tid], lbin[tid]);
}

// ---- pass B: exclusive-scan block totals (<=64) AND 256 degree bins ----
__global__ __launch_bounds__(64) void k_scanB(
    int* __restrict__ btot, int nb, const int* __restrict__ dbins,
    int* __restrict__ dcur)
{
  int lane = threadIdx.x;
  int v = (lane < nb) ? btot[lane] : 0;
  int s = v;
  #pragma unroll
  for (int off = 1; off < 64; off <<= 1) {
    int t = __shfl_up(s, off);
    if (lane >= off) s += t;
  }
  if (lane < nb) btot[lane] = s - v;

  int4 dv = *(const int4*)(dbins + lane * 4);
  int t1 = dv.x, t2 = t1 + dv.y, t3 = t2 + dv.z, t4 = t3 + dv.w;
  int ss = t4;
  #pragma unroll
  for (int off = 1; off < 64; off <<= 1) {
    int t = __shfl_up(ss, off);
    if (lane >= off) ss += t;
  }
  int ex = ss - t4;
  dcur[lane * 4]     = ex;
  dcur[lane * 4 + 1] = ex + t1;
  dcur[lane * 4 + 2] = ex + t2;
  dcur[lane * 4 + 3] = ex + t3;
}

// ---- pass C: add block offsets ----
__global__ __launch_bounds__(1024) void k_scanC(
    int* __restrict__ rowptr, const int* __restrict__ btot, int n)
{
  int off = btot[blockIdx.x];
  if (off == 0) return;
  int i = blockIdx.x * 4096 + threadIdx.x * 4;
  #pragma unroll
  for (int k = 1; k <= 4; ++k)
    if (i + k <= n) rowptr[i + k] += off;
}

// ---- counting-sort scatter: order[] = nodes grouped by (clamped) degree ----
__global__ __launch_bounds__(1024) void k_dfill(
    const int* __restrict__ deg, int* __restrict__ dcur,
    int* __restrict__ order, int n)
{
  __shared__ int lcnt[256];
  __shared__ int lbase[256];
  int tid = threadIdx.x;
  if (tid < 256) lcnt[tid] = 0;
  __syncthreads();
  int i = blockIdx.x * 1024 + tid;
  int b = 0, slot = 0;
  bool ok = (i < n);
  if (ok) {
    b = min(deg[i], 255);
    slot = atomicAdd(&lcnt[b], 1);
  }
  __syncthreads();
  if (tid < 256 && lcnt[tid]) lbase[tid] = atomicAdd(&dcur[tid], lcnt[tid]);
  __syncthreads();
  if (ok) order[lbase[b] + slot] = i;
}

// atomic-free CSR fill using precomputed pos
__global__ __launch_bounds__(256) void k_fill(
    const int* __restrict__ src, const int* __restrict__ dst,
    const int* __restrict__ rowptr, const unsigned short* __restrict__ pos,
    int* __restrict__ adj, int ecnt)
{
  int e = (blockIdx.x * 256 + threadIdx.x) * 4;
  if (e + 3 < ecnt) {
    int4 d = *(const int4*)(dst + e);
    int4 s = *(const int4*)(src + e);
    ushort4 p = *(const ushort4*)(pos + e);
    adj[rowptr[d.x] + p.x] = s.x;
    adj[rowptr[d.y] + p.y] = s.y;
    adj[rowptr[d.z] + p.z] = s.z;
    adj[rowptr[d.w] + p.w] = s.w;
  } else {
    for (; e < ecnt; ++e)
      adj[rowptr[dst[e]] + pos[e]] = src[e];
  }
}

#define H2OF(v, i) __builtin_shufflevector((v), (v), 2*(i), 2*(i)+1)

// ---- 8 nodes per wave, one 8-lane group per node (degree-sorted order).
// Group processes its node's edges serially with register prefetch; no
// cross-group merging; all 64 lanes participate in the epilogue stores.
template<bool LAST>
__global__ __launch_bounds__(256) void k_node(
    const _Float16* __restrict__ qh, const _Float16* __restrict__ kvh,
    const int* __restrict__ rowptr, const int* __restrict__ adj,
    const int* __restrict__ order,
    const float* __restrict__ sskip, float* __restrict__ outp,
    _Float16* __restrict__ xbnext, int n)
{
  int wid = (blockIdx.x * blockDim.x + threadIdx.x) >> 6;
  int lane = threadIdx.x & 63;
  const int g = lane >> 3;   // node slot within wave
  const int t = lane & 7;    // dim-chunk (dims 8t..8t+7)

  int idx = wid * 8 + g;
  bool nok = (idx < n);
  int node = order[nok ? idx : (n - 1)];

  const h8 q8 = *(const h8*)(qh + (size_t)node * DD + t * 8);
  const h2 qp0 = H2OF(q8, 0), qp1 = H2OF(q8, 1), qp2 = H2OF(q8, 2), qp3 = H2OF(q8, 3);

  const int e0 = rowptr[node];
  const int d  = nok ? (rowptr[node + 1] - e0) : 0;

  int dm = d;
  dm = max(dm, __shfl_xor(dm, 8));
  dm = max(dm, __shfl_xor(dm, 16));
  dm = max(dm, __shfl_xor(dm, 32));   // wave-max degree

  float mg = -1e30f, den = 0.f;
  float agg[8] = {0.f, 0.f, 0.f, 0.f, 0.f, 0.f, 0.f, 0.f};

  const char* kvb = (const char*)kvh;
  h8 kP, vP;
  if (d > 0) {
    int s = adj[e0];
    unsigned off = ((unsigned)s << 8) + ((unsigned)t << 4);
    kP = *(const h8*)(kvb + off);
    vP = *(const h8*)(kvb + off + 128);
  }

  for (int it = 0; it < dm; ++it) {
    const h8 kc = kP, vc = vP;
    const bool valid = (it < d);
    if (it + 1 < d) {                       // prefetch next edge (exec-masked)
      int s2 = adj[e0 + it + 1];
      unsigned off = ((unsigned)s2 << 8) + ((unsigned)t << 4);
      kP = *(const h8*)(kvb + off);
      vP = *(const h8*)(kvb + off + 128);
    }

#if __has_builtin(__builtin_amdgcn_fdot2)
    float p = __builtin_amdgcn_fdot2(qp0, H2OF(kc, 0), 0.f, false);
    p = __builtin_amdgcn_fdot2(qp1, H2OF(kc, 1), p, false);
    p = __builtin_amdgcn_fdot2(qp2, H2OF(kc, 2), p, false);
    p = __builtin_amdgcn_fdot2(qp3, H2OF(kc, 3), p, false);
#else
    h2 ph = qp0 * H2OF(kc, 0);
    ph = qp1 * H2OF(kc, 1) + ph;
    ph = qp2 * H2OF(kc, 2) + ph;
    ph = qp3 * H2OF(kc, 3) + ph;
    float p = (float)ph.x + (float)ph.y;
#endif
    p += __shfl_xor(p, 1);
    p += __shfl_xor(p, 2);
    p += __shfl_xor(p, 4);     // p replicated within the 8-lane group
    p *= 0.125f;               // 1/sqrt(64)

    if (valid && p > mg) {     // group-uniform, rare after warmup
      float c = __expf(mg - p);
      den *= c;
      #pragma unroll
      for (int j = 0; j < 8; ++j) agg[j] *= c;
      mg = p;
    }
    float w = valid ? __expf(p - mg) : 0.f;
    den += w;
    #pragma unroll
    for (int j = 0; j < 8; ++j)
      agg[j] = fmaf(w, (float)vc[j], agg[j]);
  }

  if (nok) {
    float inv = (den > 0.f) ? (1.0f / den) : 0.f;
    const float* sp = sskip + (size_t)node * DD + t * 8;
    float4 sa = *(const float4*)(sp);
    float4 sb = *(const float4*)(sp + 4);
    float r[8];
    r[0] = fmaxf(fmaf(agg[0], inv, sa.x), 0.f);
    r[1] = fmaxf(fmaf(agg[1], inv, sa.y), 0.f);
    r[2] = fmaxf(fmaf(agg[2], inv, sa.z), 0.f);
    r[3] = fmaxf(fmaf(agg[3], inv, sa.w), 0.f);
    r[4] = fmaxf(fmaf(agg[4], inv, sb.x), 0.f);
    r[5] = fmaxf(fmaf(agg[5], inv, sb.y), 0.f);
    r[6] = fmaxf(fmaf(agg[6], inv, sb.z), 0.f);
    r[7] = fmaxf(fmaf(agg[7], inv, sb.w), 0.f);
    if (LAST) {
      float* op = outp + (size_t)node * DD + t * 8;
      *(float4*)(op)     = make_float4(r[0], r[1], r[2], r[3]);
      *(float4*)(op + 4) = make_float4(r[4], r[5], r[6], r[7]);
    } else {
      h8 xh;
      #pragma unroll
      for (int j = 0; j < 8; ++j) xh[j] = (_Float16)r[j];
      *(h8*)(xbnext + (size_t)node * DD + t * 8) = xh;
    }
  }
}

// batch is sorted: run-length accumulate per wave, flush on graph change
__global__ __launch_bounds__(64) void k_pool_sum(
    const float* __restrict__ x, const int* __restrict__ batch,
    float* __restrict__ gsum, float* __restrict__ gcnt, int n)
{
  int lane = threadIdx.x;
  int n0 = blockIdx.x * 64;
  if (n0 >= n) return;
  int n1 = min(n0 + 64, n);
  float acc = 0.f;
  int g_prev = batch[n0];
  int run = 0;
  for (int nn = n0; nn < n1; ++nn) {
    int g = batch[nn];
    if (g != g_prev) {
      atomicAdd(gsum + (size_t)g_prev * DD + lane, acc);
      if (lane == 0) atomicAdd(gcnt + g_prev, (float)run);
      acc = 0.f; run = 0; g_prev = g;
    }
    acc += x[(size_t)nn * DD + lane];
    run++;
  }
  atomicAdd(gsum + (size_t)g_prev * DD + lane, acc);
  if (lane == 0) atomicAdd(gcnt + g_prev, (float)run);
}

__global__ __launch_bounds__(256) void k_pool_div(
    const float* __restrict__ gsum, const float* __restrict__ gcnt,
    float* __restrict__ emb, int gtot)
{
  int gid = blockIdx.x * blockDim.x + threadIdx.x;
  if (gid >= gtot * DD) return;
  int g = gid >> 6;
  emb[gid] = gsum[gid] / fmaxf(gcnt[g], 1.0f);
}

extern "C" void kernel_launch(void* const* d_in, const int* in_sizes, int n_in,
                              void* d_out, int out_size, void* d_ws, size_t ws_size,
                              hipStream_t stream)
{
  const float* x_in  = (const float*)d_in[0];
  const int*   ei    = (const int*)  d_in[1];
  const int*   batch = (const int*)  d_in[2];
  const float* Wq = (const float*)d_in[3];
  const float* bq = (const float*)d_in[4];
  const float* Wk = (const float*)d_in[5];
  const float* bk = (const float*)d_in[6];
  const float* Wv = (const float*)d_in[7];
  const float* bv = (const float*)d_in[8];
  const float* Ws = (const float*)d_in[9];
  const float* bs = (const float*)d_in[10];

  const int nd     = in_sizes[0];             // N*D
  const int n      = nd / DD;                 // N
  const int ecnt   = in_sizes[1] / 2;         // E
  const int layers = in_sizes[3] / (DD * DD); // L
  const int gtot   = (out_size - nd) / DD;    // G

  const int* src = ei;
  const int* dst = ei + ecnt;

  // workspace layout (16B-aligned blocks first); deg and dbins adjacent so
  // one memset covers both.
  char* cur = (char*)d_ws;
  float*     P0  = (float*)cur;     cur += (size_t)nd * 4;        // fp32 skip S
  _Float16*  XB  = (_Float16*)cur;  cur += (size_t)nd * 2;        // fp16 x
  _Float16*  QH  = (_Float16*)cur;  cur += (size_t)nd * 2;        // fp16 Q
  _Float16*  KVH = (_Float16*)cur;  cur += (size_t)nd * 4;        // fp16 K|V
  _Float16*  WF  = (_Float16*)cur;  cur += (size_t)layers * 16384 * 2; // W frags
  int* rowptr = (int*)cur;          cur += (size_t)(n + 4) * 4;
  int* adj    = (int*)cur;          cur += (size_t)(ecnt + 8) * 4;
  int* deg    = (int*)cur;          cur += (size_t)n * 4;
  int* dbins  = (int*)cur;          cur += 256 * 4;   // memset with deg
  int* dcur   = (int*)cur;          cur += 256 * 4;
  int* btot   = (int*)cur;          cur += 64 * 4;
  int* order  = (int*)cur;          cur += (size_t)n * 4;
  unsigned short* pos = (unsigned short*)cur; cur += (size_t)ecnt * 2;
  float* gsum = (float*)cur;        cur += (size_t)gtot * DD * 4;
  float* gcnt = (float*)cur;

  float* out = (float*)d_out;

  // ---- one-time prep: W fragments, x fp16, CSR + degree-sorted order ----
  k_wconv<<<layers * 32, 64, 0, stream>>>(Wq, Wk, Wv, Ws, WF);
  k_xconv<<<(n * 8 + 255) / 256, 256, 0, stream>>>(x_in, XB, n * 8);
  hipMemsetAsync(deg, 0, (size_t)(n + 256) * 4, stream);  // deg + dbins
  const int eb4 = (ecnt + 1023) / 1024;
  k_hist<<<eb4, 256, 0, stream>>>(dst, deg, pos, ecnt);
  const int nbk = (n + 4095) / 4096;
  k_scanA<<<nbk, 1024, 0, stream>>>(deg, rowptr, btot, dbins, n);
  k_scanB<<<1, 64, 0, stream>>>(btot, nbk, dbins, dcur);
  k_scanC<<<nbk, 1024, 0, stream>>>(rowptr, btot, n);
  k_dfill<<<(n + 1023) / 1024, 1024, 0, stream>>>(deg, dcur, order, n);
  k_fill<<<eb4, 256, 0, stream>>>(src, dst, rowptr, pos, adj, ecnt);

  const int pj = (n + 63) / 64;
  const int nb = (n + 31) / 32;   // 8 nodes/wave, 4 waves/block

  for (int l = 0; l < layers; ++l) {
    const size_t bo = (size_t)l * DD;
    k_projM<<<pj, 256, 0, stream>>>(XB, WF + (size_t)l * 16384,
                                    bq + bo, bk + bo, bv + bo, bs + bo,
                                    QH, KVH, P0, n);
    if (l == layers - 1)
      k_node<true><<<nb, 256, 0, stream>>>(QH, KVH, rowptr, adj, order,
                                           P0, out, XB, n);
    else
      k_node<false><<<nb, 256, 0, stream>>>(QH, KVH, rowptr, adj, order,
                                            P0, out, XB, n);
  }

  hipMemsetAsync(gsum, 0, (size_t)(gtot * DD + gtot) * 4, stream);
  const int pbk = (n + 63) / 64;
  k_pool_sum<<<pbk, 64, 0, stream>>>(out, batch, gsum, gcnt, n);
  const int fb = (gtot * DD + 255) / 256;
  k_pool_div<<<fb, 256, 0, stream>>>(gsum, gcnt, out + (size_t)nd, gtot);
}

// Round 9
// 350.155 us; speedup vs baseline: 1.2017x; 1.0016x over previous
//
#include <hip/hip_runtime.h>
#include <math.h>

#define DD 64   // feature dim
#define APAD 512 // adj zero-pad (branch-free over-read)

typedef _Float16 h2 __attribute__((ext_vector_type(2)));
typedef _Float16 h4 __attribute__((ext_vector_type(4)));
typedef _Float16 h8 __attribute__((ext_vector_type(8)));
typedef float f32x4 __attribute__((ext_vector_type(4)));

// ---- W -> MFMA A-fragment pre-shuffle (fp16), all layers at once ----
__global__ __launch_bounds__(64) void k_wconv(
    const float* __restrict__ Wq, const float* __restrict__ Wk,
    const float* __restrict__ Wv, const float* __restrict__ Ws,
    _Float16* __restrict__ wf)
{
  int bid = blockIdx.x;          // layer*32 + c*2 + s
  int layer = bid >> 5;
  int c = (bid >> 1) & 15;
  int s = bid & 1;
  int lane = threadIdx.x;
  int col = c * 16 + (lane & 15);
  int mi = col >> 6;
  const float* W = (mi == 0 ? Wq : mi == 1 ? Wk : mi == 2 ? Wv : Ws)
                   + (size_t)layer * DD * DD;
  int colw = col & 63;
  _Float16* o = wf + ((((size_t)(layer * 16 + c)) * 2 + s) * 64 + lane) * 8;
  #pragma unroll
  for (int j = 0; j < 8; ++j) {
    int k = s * 32 + (lane >> 4) * 8 + j;
    o[j] = (_Float16)W[k * DD + colw];
  }
}

// fp32 -> fp16 convert (8 elems/thread)
__global__ __launch_bounds__(256) void k_xconv(
    const float* __restrict__ x, _Float16* __restrict__ xb, int total8)
{
  int i = blockIdx.x * 256 + threadIdx.x;
  if (i >= total8) return;
  float4 a = ((const float4*)x)[i * 2];
  float4 b = ((const float4*)x)[i * 2 + 1];
  h8 o;
  o[0] = (_Float16)a.x; o[1] = (_Float16)a.y; o[2] = (_Float16)a.z; o[3] = (_Float16)a.w;
  o[4] = (_Float16)b.x; o[5] = (_Float16)b.y; o[6] = (_Float16)b.z; o[7] = (_Float16)b.w;
  *(h8*)(xb + (size_t)i * 8) = o;
}

// ---- MFMA projection, swapped operands + per-wave LDS staging ----
// Outputs: qh fp16 [n][64], kvh fp16 [n][128] (K|V), sh fp16 [n][64] (skip).
#define LH_STRIDE 200   // halves per node row (192 used + 8 pad) = 400B
#define LS_STRIDE 72    // halves per node row (64 used + 8 pad)  = 144B
#define WAVE_LDS  (16 * 400 + 16 * 144)   // 8704B

__global__ __launch_bounds__(256) void k_projM(
    const _Float16* __restrict__ xb, const _Float16* __restrict__ wf,
    const float* __restrict__ bq, const float* __restrict__ bk,
    const float* __restrict__ bv, const float* __restrict__ bs,
    _Float16* __restrict__ qh, _Float16* __restrict__ kvh,
    _Float16* __restrict__ sh, int n)
{
  __shared__ __align__(16) char lds[4 * WAVE_LDS];
  int wave = threadIdx.x >> 6;
  int lane = threadIdx.x & 63;
  int nbase = blockIdx.x * 64 + wave * 16;
  if (nbase >= n) return;

  char* wbase = lds + wave * WAVE_LDS;
  _Float16* lh = (_Float16*)wbase;                 // [16][LH_STRIDE] QKV
  _Float16* ls = (_Float16*)(wbase + 16 * 400);    // [16][LS_STRIDE] S

  const int cl = lane & 15;
  const int rq = lane >> 4;

  int ar = min(nbase + cl, n - 1);
  h8 a0 = *(const h8*)(xb + (size_t)ar * DD + rq * 8);
  h8 a1 = *(const h8*)(xb + (size_t)ar * DD + 32 + rq * 8);

  #pragma unroll
  for (int c = 0; c < 16; ++c) {
    const float* bp = (c < 4) ? bq : (c < 8) ? bk : (c < 12) ? bv : bs;
    const int fb = c * 16 + rq * 4;          // global feature base (0..255)
    float4 b4 = *(const float4*)(bp + (fb & 63));
    f32x4 acc; acc[0] = b4.x; acc[1] = b4.y; acc[2] = b4.z; acc[3] = b4.w;
    const _Float16* wp = wf + ((size_t)(c * 2) * 64 + lane) * 8;
    h8 w0 = *(const h8*)(wp);
    h8 w1 = *(const h8*)(wp + 64 * 8);
    acc = __builtin_amdgcn_mfma_f32_16x16x32_f16(w0, a0, acc, 0, 0, 0);
    acc = __builtin_amdgcn_mfma_f32_16x16x32_f16(w1, a1, acc, 0, 0, 0);

    h4 o; o[0] = (_Float16)acc[0]; o[1] = (_Float16)acc[1];
    o[2] = (_Float16)acc[2]; o[3] = (_Float16)acc[3];
    if (c < 12)
      *(h4*)(lh + cl * LH_STRIDE + fb) = o;
    else
      *(h4*)(ls + cl * LS_STRIDE + (fb - 192)) = o;
  }

  // QH: 16 nodes x 128B
  #pragma unroll
  for (int i = 0; i < 2; ++i) {
    int chunk = i * 64 + lane;
    int nd = chunk >> 3, co = chunk & 7;
    h8 v = *(const h8*)(lh + nd * LH_STRIDE + co * 8);
    if (nbase + nd < n)
      *(h8*)(qh + (size_t)(nbase + nd) * DD + co * 8) = v;
  }
  // KVH: 16 nodes x 256B
  #pragma unroll
  for (int i = 0; i < 4; ++i) {
    int chunk = i * 64 + lane;
    int nd = chunk >> 4, co = chunk & 15;
    h8 v = *(const h8*)(lh + nd * LH_STRIDE + 64 + co * 8);
    if (nbase + nd < n)
      *(h8*)(kvh + (size_t)(nbase + nd) * 128 + co * 8) = v;
  }
  // S: 16 nodes x 128B fp16
  #pragma unroll
  for (int i = 0; i < 2; ++i) {
    int chunk = i * 64 + lane;
    int nd = chunk >> 3, co = chunk & 7;
    h8 v = *(const h8*)(ls + nd * LS_STRIDE + co * 8);
    if (nbase + nd < n)
      *(h8*)(sh + (size_t)(nbase + nd) * DD + co * 8) = v;
  }
}

// ---- CSR build ----
__global__ __launch_bounds__(256) void k_hist(
    const int* __restrict__ dst, int* __restrict__ deg,
    unsigned short* __restrict__ pos, int ecnt)
{
  int e = (blockIdx.x * 256 + threadIdx.x) * 4;
  if (e + 3 < ecnt) {
    int4 d = *(const int4*)(dst + e);
    pos[e]     = (unsigned short)atomicAdd(deg + d.x, 1);
    pos[e + 1] = (unsigned short)atomicAdd(deg + d.y, 1);
    pos[e + 2] = (unsigned short)atomicAdd(deg + d.z, 1);
    pos[e + 3] = (unsigned short)atomicAdd(deg + d.w, 1);
  } else {
    for (; e < ecnt; ++e)
      pos[e] = (unsigned short)atomicAdd(deg + dst[e], 1);
  }
}

// ---- parallel scan pass A: block-local scan + degree histogram (fused) ----
__global__ __launch_bounds__(1024) void k_scanA(
    const int* __restrict__ deg, int* __restrict__ rowptr,
    int* __restrict__ btot, int* __restrict__ dbins, int n)
{
  __shared__ int wsum[16];
  __shared__ int lbin[256];
  int tid = threadIdx.x;
  int lane = tid & 63, wave = tid >> 6;
  if (tid < 256) lbin[tid] = 0;
  __syncthreads();
  int i = blockIdx.x * 4096 + tid * 4;
  int4 d = make_int4(0, 0, 0, 0);
  if (i + 3 < n) d = *(const int4*)(deg + i);
  else {
    if (i     < n) d.x = deg[i];
    if (i + 1 < n) d.y = deg[i + 1];
    if (i + 2 < n) d.z = deg[i + 2];
  }
  if (i     < n) atomicAdd(&lbin[min(d.x, 255)], 1);
  if (i + 1 < n) atomicAdd(&lbin[min(d.y, 255)], 1);
  if (i + 2 < n) atomicAdd(&lbin[min(d.z, 255)], 1);
  if (i + 3 < n) atomicAdd(&lbin[min(d.w, 255)], 1);

  int s1 = d.x, s2 = s1 + d.y, s3 = s2 + d.z, s4 = s3 + d.w;
  int s = s4;
  #pragma unroll
  for (int off = 1; off < 64; off <<= 1) {
    int t = __shfl_up(s, off);
    if (lane >= off) s += t;
  }
  if (lane == 63) wsum[wave] = s;
  __syncthreads();
  if (wave == 0) {
    int ws = (lane < 16) ? wsum[lane] : 0;
    #pragma unroll
    for (int off = 1; off < 16; off <<= 1) {
      int t = __shfl_up(ws, off);
      if (lane >= off) ws += t;
    }
    if (lane < 16) wsum[lane] = ws;
  }
  __syncthreads();
  int excl = ((wave > 0) ? wsum[wave - 1] : 0) + s - s4;
  if (i     < n) rowptr[i + 1] = excl + s1;
  if (i + 1 < n) rowptr[i + 2] = excl + s2;
  if (i + 2 < n) rowptr[i + 3] = excl + s3;
  if (i + 3 < n) rowptr[i + 4] = excl + s4;
  if (tid == 0) {
    if (blockIdx.x == 0) rowptr[0] = 0;
    btot[blockIdx.x] = wsum[15];
  }
  if (tid < 256 && lbin[tid]) atomicAdd(&dbins[tid], lbin[tid]);
}

// ---- pass B: exclusive-scan block totals (<=64) AND 256 degree bins ----
__global__ __launch_bounds__(64) void k_scanB(
    int* __restrict__ btot, int nb, const int* __restrict__ dbins,
    int* __restrict__ dcur)
{
  int lane = threadIdx.x;
  int v = (lane < nb) ? btot[lane] : 0;
  int s = v;
  #pragma unroll
  for (int off = 1; off < 64; off <<= 1) {
    int t = __shfl_up(s, off);
    if (lane >= off) s += t;
  }
  if (lane < nb) btot[lane] = s - v;

  int4 dv = *(const int4*)(dbins + lane * 4);
  int t1 = dv.x, t2 = t1 + dv.y, t3 = t2 + dv.z, t4 = t3 + dv.w;
  int ss = t4;
  #pragma unroll
  for (int off = 1; off < 64; off <<= 1) {
    int t = __shfl_up(ss, off);
    if (lane >= off) ss += t;
  }
  int ex = ss - t4;
  dcur[lane * 4]     = ex;
  dcur[lane * 4 + 1] = ex + t1;
  dcur[lane * 4 + 2] = ex + t2;
  dcur[lane * 4 + 3] = ex + t3;
}

// ---- pass C: add block offsets ----
__global__ __launch_bounds__(1024) void k_scanC(
    int* __restrict__ rowptr, const int* __restrict__ btot, int n)
{
  int off = btot[blockIdx.x];
  if (off == 0) return;
  int i = blockIdx.x * 4096 + threadIdx.x * 4;
  #pragma unroll
  for (int k = 1; k <= 4; ++k)
    if (i + k <= n) rowptr[i + k] += off;
}

// ---- counting-sort scatter: order[] = nodes grouped by (clamped) degree ----
__global__ __launch_bounds__(1024) void k_dfill(
    const int* __restrict__ deg, int* __restrict__ dcur,
    int* __restrict__ order, int n)
{
  __shared__ int lcnt[256];
  __shared__ int lbase[256];
  int tid = threadIdx.x;
  if (tid < 256) lcnt[tid] = 0;
  __syncthreads();
  int i = blockIdx.x * 1024 + tid;
  int b = 0, slot = 0;
  bool ok = (i < n);
  if (ok) {
    b = min(deg[i], 255);
    slot = atomicAdd(&lcnt[b], 1);
  }
  __syncthreads();
  if (tid < 256 && lcnt[tid]) lbase[tid] = atomicAdd(&dcur[tid], lcnt[tid]);
  __syncthreads();
  if (ok) order[lbase[b] + slot] = i;
}

// atomic-free CSR fill using precomputed pos
__global__ __launch_bounds__(256) void k_fill(
    const int* __restrict__ src, const int* __restrict__ dst,
    const int* __restrict__ rowptr, const unsigned short* __restrict__ pos,
    int* __restrict__ adj, int ecnt)
{
  int e = (blockIdx.x * 256 + threadIdx.x) * 4;
  if (e + 3 < ecnt) {
    int4 d = *(const int4*)(dst + e);
    int4 s = *(const int4*)(src + e);
    ushort4 p = *(const ushort4*)(pos + e);
    adj[rowptr[d.x] + p.x] = s.x;
    adj[rowptr[d.y] + p.y] = s.y;
    adj[rowptr[d.z] + p.z] = s.z;
    adj[rowptr[d.w] + p.w] = s.w;
  } else {
    for (; e < ecnt; ++e)
      adj[rowptr[dst[e]] + pos[e]] = src[e];
  }
}

#define H2OF(v, i) __builtin_shufflevector((v), (v), 2*(i), 2*(i)+1)

// ---- 8 nodes per wave, one 8-lane group per node (degree-sorted order).
// 2-deep edge pipeline: adj prefetched 2 pairs ahead, K/V 1 pair ahead.
// Branch-free over-read into the zeroed adj pad (clamped to elim).
template<bool LAST>
__global__ __launch_bounds__(256) void k_node(
    const _Float16* __restrict__ qh, const _Float16* __restrict__ kvh,
    const int* __restrict__ rowptr, const int* __restrict__ adj,
    const int* __restrict__ order,
    const _Float16* __restrict__ sh, float* __restrict__ outp,
    _Float16* __restrict__ xbnext, int n, int elim)
{
  int wid = (blockIdx.x * blockDim.x + threadIdx.x) >> 6;
  int lane = threadIdx.x & 63;
  const int g = lane >> 3;   // node slot within wave
  const int t = lane & 7;    // dim-chunk (dims 8t..8t+7)

  int idx = wid * 8 + g;
  bool nok = (idx < n);
  int node = order[nok ? idx : (n - 1)];

  const h8 q8 = *(const h8*)(qh + (size_t)node * DD + t * 8);
  const h2 qp0 = H2OF(q8, 0), qp1 = H2OF(q8, 1), qp2 = H2OF(q8, 2), qp3 = H2OF(q8, 3);

  const int e0 = rowptr[node];
  const int d  = nok ? (rowptr[node + 1] - e0) : 0;

  int dm = d;
  dm = max(dm, __shfl_xor(dm, 8));
  dm = max(dm, __shfl_xor(dm, 16));
  dm = max(dm, __shfl_xor(dm, 32));   // wave-max degree

  float mg = -1e30f, den = 0.f;
  float agg[8] = {0.f, 0.f, 0.f, 0.f, 0.f, 0.f, 0.f, 0.f};

  const char* kvb = (const char*)kvh;
  const unsigned tb = (unsigned)t << 4;

  // pipeline prologue: KV for edges 0,1 ; adj values for edges 2,3
  h8 kA, vA, kB, vB;
  {
    int a0 = adj[min(e0,     elim)];
    int a1 = adj[min(e0 + 1, elim)];
    unsigned o0 = ((unsigned)a0 << 8) + tb;
    unsigned o1 = ((unsigned)a1 << 8) + tb;
    kA = *(const h8*)(kvb + o0); vA = *(const h8*)(kvb + o0 + 128);
    kB = *(const h8*)(kvb + o1); vB = *(const h8*)(kvb + o1 + 128);
  }
  int aN0 = adj[min(e0 + 2, elim)];
  int aN1 = adj[min(e0 + 3, elim)];

  for (int it = 0; it < dm; it += 2) {
    // adj for pair+2
    int aF0 = adj[min(e0 + it + 4, elim)];
    int aF1 = adj[min(e0 + it + 5, elim)];
    // KV for pair+1 (uses adj fetched last pair)
    unsigned o0 = ((unsigned)aN0 << 8) + tb;
    unsigned o1 = ((unsigned)aN1 << 8) + tb;
    h8 kN0 = *(const h8*)(kvb + o0); h8 vN0 = *(const h8*)(kvb + o0 + 128);
    h8 kN1 = *(const h8*)(kvb + o1); h8 vN1 = *(const h8*)(kvb + o1 + 128);

#define EDGE_STEP(KC, VC, VALID)                                        \
    {                                                                   \
      bool valid = (VALID);                                             \
      float p;                                                          \
      {                                                                 \
        _Pragma("clang diagnostic push")                                \
        p = 0.f;                                                        \
        _Pragma("clang diagnostic pop")                                 \
      }                                                                 \
      p = (float)(KC)[0] * (float)q8[0] + p;                            \
      p = fmaf((float)(KC)[1], (float)q8[1], p);                        \
      p = fmaf((float)(KC)[2], (float)q8[2], p);                        \
      p = fmaf((float)(KC)[3], (float)q8[3], p);                        \
      p = fmaf((float)(KC)[4], (float)q8[4], p);                        \
      p = fmaf((float)(KC)[5], (float)q8[5], p);                        \
      p = fmaf((float)(KC)[6], (float)q8[6], p);                        \
      p = fmaf((float)(KC)[7], (float)q8[7], p);                        \
      p += __shfl_xor(p, 1);                                            \
      p += __shfl_xor(p, 2);                                            \
      p += __shfl_xor(p, 4);                                            \
      p *= 0.125f;                                                      \
      if (valid && p > mg) {                                            \
        float c = __expf(mg - p);                                       \
        den *= c;                                                       \
        _Pragma("unroll")                                               \
        for (int j = 0; j < 8; ++j) agg[j] *= c;                        \
        mg = p;                                                         \
      }                                                                 \
      float w = valid ? __expf(p - mg) : 0.f;                           \
      den += w;                                                         \
      _Pragma("unroll")                                                 \
      for (int j = 0; j < 8; ++j)                                       \
        agg[j] = fmaf(w, (float)(VC)[j], agg[j]);                       \
    }

    EDGE_STEP(kA, vA, it < d)
    EDGE_STEP(kB, vB, it + 1 < d)
#undef EDGE_STEP

    kA = kN0; vA = vN0; kB = kN1; vB = vN1;
    aN0 = aF0; aN1 = aF1;
  }

  if (nok) {
    float inv = (den > 0.f) ? (1.0f / den) : 0.f;
    const h8 s8 = *(const h8*)(sh + (size_t)node * DD + t * 8);
    float r[8];
    #pragma unroll
    for (int j = 0; j < 8; ++j)
      r[j] = fmaxf(fmaf(agg[j], inv, (float)s8[j]), 0.f);
    if (LAST) {
      float* op = outp + (size_t)node * DD + t * 8;
      *(float4*)(op)     = make_float4(r[0], r[1], r[2], r[3]);
      *(float4*)(op + 4) = make_float4(r[4], r[5], r[6], r[7]);
    } else {
      h8 xh;
      #pragma unroll
      for (int j = 0; j < 8; ++j) xh[j] = (_Float16)r[j];
      *(h8*)(xbnext + (size_t)node * DD + t * 8) = xh;
    }
  }
}

// batch is sorted: run-length accumulate per wave, flush on graph change
__global__ __launch_bounds__(64) void k_pool_sum(
    const float* __restrict__ x, const int* __restrict__ batch,
    float* __restrict__ gsum, float* __restrict__ gcnt, int n)
{
  int lane = threadIdx.x;
  int n0 = blockIdx.x * 64;
  if (n0 >= n) return;
  int n1 = min(n0 + 64, n);
  float acc = 0.f;
  int g_prev = batch[n0];
  int run = 0;
  for (int nn = n0; nn < n1; ++nn) {
    int g = batch[nn];
    if (g != g_prev) {
      atomicAdd(gsum + (size_t)g_prev * DD + lane, acc);
      if (lane == 0) atomicAdd(gcnt + g_prev, (float)run);
      acc = 0.f; run = 0; g_prev = g;
    }
    acc += x[(size_t)nn * DD + lane];
    run++;
  }
  atomicAdd(gsum + (size_t)g_prev * DD + lane, acc);
  if (lane == 0) atomicAdd(gcnt + g_prev, (float)run);
}

__global__ __launch_bounds__(256) void k_pool_div(
    const float* __restrict__ gsum, const float* __restrict__ gcnt,
    float* __restrict__ emb, int gtot)
{
  int gid = blockIdx.x * blockDim.x + threadIdx.x;
  if (gid >= gtot * DD) return;
  int g = gid >> 6;
  emb[gid] = gsum[gid] / fmaxf(gcnt[g], 1.0f);
}

extern "C" void kernel_launch(void* const* d_in, const int* in_sizes, int n_in,
                              void* d_out, int out_size, void* d_ws, size_t ws_size,
                              hipStream_t stream)
{
  const float* x_in  = (const float*)d_in[0];
  const int*   ei    = (const int*)  d_in[1];
  const int*   batch = (const int*)  d_in[2];
  const float* Wq = (const float*)d_in[3];
  const float* bq = (const float*)d_in[4];
  const float* Wk = (const float*)d_in[5];
  const float* bk = (const float*)d_in[6];
  const float* Wv = (const float*)d_in[7];
  const float* bv = (const float*)d_in[8];
  const float* Ws = (const float*)d_in[9];
  const float* bs = (const float*)d_in[10];

  const int nd     = in_sizes[0];             // N*D
  const int n      = nd / DD;                 // N
  const int ecnt   = in_sizes[1] / 2;         // E
  const int layers = in_sizes[3] / (DD * DD); // L
  const int gtot   = (out_size - nd) / DD;    // G

  const int* src = ei;
  const int* dst = ei + ecnt;

  // workspace layout; adj pad, deg, dbins adjacent -> one memset covers all
  char* cur = (char*)d_ws;
  _Float16*  SH  = (_Float16*)cur;  cur += (size_t)nd * 2;        // fp16 skip S
  _Float16*  XB  = (_Float16*)cur;  cur += (size_t)nd * 2;        // fp16 x
  _Float16*  QH  = (_Float16*)cur;  cur += (size_t)nd * 2;        // fp16 Q
  _Float16*  KVH = (_Float16*)cur;  cur += (size_t)nd * 4;        // fp16 K|V
  _Float16*  WF  = (_Float16*)cur;  cur += (size_t)layers * 16384 * 2; // W frags
  int* rowptr = (int*)cur;          cur += (size_t)(n + 4) * 4;
  int* adj    = (int*)cur;          cur += (size_t)(ecnt + APAD) * 4;
  int* deg    = (int*)cur;          cur += (size_t)n * 4;
  int* dbins  = (int*)cur;          cur += 256 * 4;
  int* dcur   = (int*)cur;          cur += 256 * 4;
  int* btot   = (int*)cur;          cur += 64 * 4;
  int* order  = (int*)cur;          cur += (size_t)n * 4;
  unsigned short* pos = (unsigned short*)cur; cur += (size_t)ecnt * 2;
  float* gsum = (float*)cur;        cur += (size_t)gtot * DD * 4;
  float* gcnt = (float*)cur;

  float* out = (float*)d_out;
  const int elim = ecnt + APAD - 1;

  // ---- one-time prep: W fragments, x fp16, CSR + degree-sorted order ----
  k_wconv<<<layers * 32, 64, 0, stream>>>(Wq, Wk, Wv, Ws, WF);
  k_xconv<<<(n * 8 + 255) / 256, 256, 0, stream>>>(x_in, XB, n * 8);
  hipMemsetAsync(adj + ecnt, 0, (size_t)(APAD + n + 256) * 4, stream); // pad+deg+dbins
  const int eb4 = (ecnt + 1023) / 1024;
  k_hist<<<eb4, 256, 0, stream>>>(dst, deg, pos, ecnt);
  const int nbk = (n + 4095) / 4096;
  k_scanA<<<nbk, 1024, 0, stream>>>(deg, rowptr, btot, dbins, n);
  k_scanB<<<1, 64, 0, stream>>>(btot, nbk, dbins, dcur);
  k_scanC<<<nbk, 1024, 0, stream>>>(rowptr, btot, n);
  k_dfill<<<(n + 1023) / 1024, 1024, 0, stream>>>(deg, dcur, order, n);
  k_fill<<<eb4, 256, 0, stream>>>(src, dst, rowptr, pos, adj, ecnt);

  const int pj = (n + 63) / 64;
  const int nb = (n + 31) / 32;   // 8 nodes/wave, 4 waves/block

  for (int l = 0; l < layers; ++l) {
    const size_t bo = (size_t)l * DD;
    k_projM<<<pj, 256, 0, stream>>>(XB, WF + (size_t)l * 16384,
                                    bq + bo, bk + bo, bv + bo, bs + bo,
                                    QH, KVH, SH, n);
    if (l == layers - 1)
      k_node<true><<<nb, 256, 0, stream>>>(QH, KVH, rowptr, adj, order,
                                           SH, out, XB, n, elim);
    else
      k_node<false><<<nb, 256, 0, stream>>>(QH, KVH, rowptr, adj, order,
                                            SH, out, XB, n, elim);
  }

  hipMemsetAsync(gsum, 0, (size_t)(gtot * DD + gtot) * 4, stream);
  const int pbk = (n + 63) / 64;
  k_pool_sum<<<pbk, 64, 0, stream>>>(out, batch, gsum, gcnt, n);
  const int fb = (gtot * DD + 255) / 256;
  k_pool_div<<<fb, 256, 0, stream>>>(gsum, gcnt, out + (size_t)nd, gtot);
}